// Round 17
// baseline (208.115 us; speedup 1.0000x reference)
//
#include <hip/hip_runtime.h>
#include <hip/hip_bf16.h>

typedef unsigned short u16;
typedef unsigned int u32;
typedef __attribute__((ext_vector_type(8))) short bf16x8;
typedef __attribute__((ext_vector_type(4))) float f32x4;
typedef __attribute__((ext_vector_type(4))) u16 u16x4;
typedef __attribute__((ext_vector_type(8))) u16 u16x8;

#define B_ 64
#define R_ 2
#define T_ 32
#define N_ 128
#define C_ 64

__device__ __forceinline__ u16 f2bf(float f) {
  return __builtin_bit_cast(u16, __float2bfloat16(f));
}
__device__ __forceinline__ float bf2f(u16 h) {
  u32 u = ((u32)h) << 16;
  return __builtin_bit_cast(float, u);
}

#define MFMA __builtin_amdgcn_mfma_f32_16x16x32_bf16

#define STG16(gsrc, ldst)                                                   \
  __builtin_amdgcn_global_load_lds(                                         \
      (const __attribute__((address_space(1))) u32*)(gsrc),                 \
      (__attribute__((address_space(3))) u32*)(ldst), 16, 0, 0)

// barrier that does NOT drain vmcnt
#define BAR()                                                  \
  do {                                                         \
    asm volatile("s_waitcnt lgkmcnt(0)" ::: "memory");         \
    __builtin_amdgcn_s_barrier();                              \
    __builtin_amdgcn_sched_barrier(0);                         \
  } while (0)

// counted vmcnt wait. N = number of LOADS issued after the op we need
// complete (stores may retire early/out-of-order on CDNA -> never counted).
#define WAITVM(N)                                              \
  do {                                                         \
    asm volatile("s_waitcnt vmcnt(" #N ")" ::: "memory");      \
    __builtin_amdgcn_sched_barrier(0);                         \
  } while (0)

// ---- issue one 16KB chunk (32 rows x 128 f32) via global_load_lds.
__device__ __forceinline__ void gl_chunk(const float* Abase, float* rb,
                                         int w, int lane) {
#pragma unroll
  for (int g = 0; g < 4; ++g) {
    const int d = (w * 4 + g) * 64 + lane;
    const int c4 = d >> 5;
    const int rl = (d & 31) ^ (c4 & 7);
    STG16(Abase + rl * 128 + c4 * 4, rb + (w * 4 + g) * 256);
  }
}

// ---- consume a landed chunk (R10/R15-proven).
__device__ __forceinline__ void consume(const float* rb, int ch,
                                        u16 (*ATb)[32], float* outAs,
                                        float* dscr, int tid, float4* gv) {
  const int c4 = tid & 31, rb8 = tid >> 5;
  const float4* rf4 = (const float4*)rb;
#pragma unroll
  for (int j = 0; j < 4; ++j)
    gv[j] = rf4[c4 * 32 + (((rb8 << 2) + j) ^ (c4 & 7))];
  float d4[4];
#pragma unroll
  for (int j = 0; j < 4; ++j) {
    float s = (gv[j].x + gv[j].y) + (gv[j].z + gv[j].w);
    s += __shfl_xor(s, 1); s += __shfl_xor(s, 2); s += __shfl_xor(s, 4);
    s += __shfl_xor(s, 8); s += __shfl_xor(s, 16);
    d4[j] = rsqrtf(s + 1.0f);
  }
  if (c4 == 0) {
    float4 dv = {d4[0], d4[1], d4[2], d4[3]};
    *(float4*)(dscr + ch * 32 + rb8 * 4) = dv;
  }
#pragma unroll
  for (int j = 0; j < 4; ++j)
    *(float4*)(outAs + (size_t)(ch * 32 + rb8 * 4 + j) * N_ + c4 * 4) = gv[j];
  const int nb = (rb8 << 2) ^ ((c4 & 7) << 2);
#pragma unroll
  for (int i = 0; i < 4; ++i) {
    const int m = c4 * 4 + i;
    u16x4 pk;
#pragma unroll
    for (int j = 0; j < 4; ++j) {
      float v = ((const float*)&gv[j])[i];
      if (m == ch * 32 + rb8 * 4 + j) v += 1.0f;
      pk[j] = f2bf(v * d4[j]);
    }
    *(u16x4*)&ATb[m][nb] = pk;
  }
}

__device__ __forceinline__ void load_wg(bf16x8 wf[2][2], const float* wg, int r,
                                        int wr, int lr, int lg) {
#pragma unroll
  for (int kk = 0; kk < 2; ++kk)
#pragma unroll
    for (int mr = 0; mr < 2; ++mr) {
      const float* p = wg + ((size_t)(r * C_ + 32 * wr + 16 * mr + lr)) * C_ + 32 * kk + 8 * lg;
      float4 a = *(const float4*)p, b = *(const float4*)(p + 4);
      bf16x8 f;
      f[0] = (short)f2bf(a.x); f[1] = (short)f2bf(a.y);
      f[2] = (short)f2bf(a.z); f[3] = (short)f2bf(a.w);
      f[4] = (short)f2bf(b.x); f[5] = (short)f2bf(b.y);
      f[6] = (short)f2bf(b.z); f[7] = (short)f2bf(b.w);
      wf[kk][mr] = f;
    }
}

// mm1: TMP[o][n ^ ((o&3)<<4)] = sum_c W[o][c]*X[c][n] + bias[o]
__device__ __forceinline__ void mm1f(u16 (*TMP)[128], const bf16x8 wf[2][2],
                                     const bf16x8 bfr[2][4], const float4 bias[2],
                                     int wr, int wc, int lr, int lg) {
  f32x4 acc1[2][4] = {};
#pragma unroll
  for (int kk = 0; kk < 2; ++kk)
#pragma unroll
    for (int mr = 0; mr < 2; ++mr)
#pragma unroll
      for (int nc = 0; nc < 4; ++nc)
        acc1[mr][nc] = MFMA(wf[kk][mr], bfr[kk][nc], acc1[mr][nc], 0, 0, 0);
#pragma unroll
  for (int mr = 0; mr < 2; ++mr) {
    const int o0 = 32 * wr + 16 * mr + 4 * lg;
    const float bb[4] = {bias[mr].x, bias[mr].y, bias[mr].z, bias[mr].w};
#pragma unroll
    for (int nc = 0; nc < 4; ++nc) {
      const int n = 64 * wc + 16 * nc + lr;
#pragma unroll
      for (int i = 0; i < 4; ++i)
        TMP[o0 + i][n ^ (i << 4)] = f2bf(acc1[mr][nc][i] + bb[i]);
    }
  }
}

// one K=32 mm2 step for chunk ch (R10-proven)
__device__ __forceinline__ void mm2k(f32x4 acc[2][4], const u16 (*TMP)[128],
                                     const u16 (*ATb)[32], int ch,
                                     int wr, int wc, int lr, int lg) {
  bf16x8 af[2], bfr[4];
#pragma unroll
  for (int mr = 0; mr < 2; ++mr) {
    const int c = 32 * wr + 16 * mr + lr;
    const int colT = (ch * 32 + 8 * lg) ^ ((lr & 3) << 4);
    af[mr] = *(const bf16x8*)&TMP[c][colT];
  }
#pragma unroll
  for (int nc = 0; nc < 4; ++nc) {
    const int m = 64 * wc + 16 * nc + lr;
    const int swz = ((m >> 2) & 7) << 2;
    const int base = (8 * lg) ^ (swz & 24);
    const int s4 = swz & 4;
    u16x4 h0 = *(const u16x4*)&ATb[m][base + s4];
    u16x4 h1 = *(const u16x4*)&ATb[m][base + (4 ^ s4)];
    bf16x8 f;
    f[0] = (short)h0[0]; f[1] = (short)h0[1]; f[2] = (short)h0[2]; f[3] = (short)h0[3];
    f[4] = (short)h1[0]; f[5] = (short)h1[1]; f[6] = (short)h1[2]; f[7] = (short)h1[3];
    bfr[nc] = f;
  }
#pragma unroll
  for (int mr = 0; mr < 2; ++mr)
#pragma unroll
    for (int nc = 0; nc < 4; ++nc)
      acc[mr][nc] = MFMA(af[mr], bfr[nc], acc[mr][nc], 0, 0, 0);
}

// ---------------------------------------------------------------------------
// K1 (R17): R15 dataflow with 2-phase prefetch depth. gl issues moved one
// phase earlier; waits 4 -> 8 (at each WAITVM(8) exactly 8 younger LOADS
// exist -> chunk forced complete; loads retire in order). XT extraction
// gets its own phase (P0b) so RB2 is dead before q2's issue in P1.
// LDS = 49152+16384+16384 = 81920 -> 2 blocks/CU; VGPR ~100 (no spill).
// ---------------------------------------------------------------------------
__global__ __launch_bounds__(256, 2) void k_gcn(
    const float* __restrict__ x, const float* __restrict__ A,
    const float* __restrict__ wg, const float* __restrict__ bg,
    float* __restrict__ outA, u16* __restrict__ wsX, float* __restrict__ dscrg) {
  __shared__ __align__(16) float RB[3][32 * 128];
  __shared__ __align__(16) u16 AT[2][N_][32];
  __shared__ __align__(16) u16 TMP[C_][128];

  const int tid = threadIdx.x;
  const int bid = ((blockIdx.x & 7) << 8) | (blockIdx.x >> 3);  // XCD swizzle
  const int b = bid >> 5, t = bid & 31;
  const int lane = tid & 63, w = tid >> 6;
  const int wr = w >> 1, wc = w & 1;
  const int lr = lane & 15, lg = lane >> 4;

  const size_t Asl0 = ((size_t)((b * R_ + 0) * T_ + t)) * (size_t)(N_ * N_);
  const size_t Asl1 = ((size_t)((b * R_ + 1) * T_ + t)) * (size_t)(N_ * N_);
  float* dscr = dscrg + (size_t)bid * 256;  // [2][128] per pair, in out-main

  // ---- prologue: xv, weights, bias; issue q0 -> RB0, q1 -> RB1
  float4 xv[8];
  {
    const int c = tid & 63, ub = tid >> 6;
    const float* xp = x + ((size_t)(b * C_ + c) * T_ + t) * N_ + 32 * ub;
#pragma unroll
    for (int j = 0; j < 8; ++j) xv[j] = *(const float4*)(xp + 4 * j);
  }
  bf16x8 wf0[2][2], wf1[2][2];
  load_wg(wf0, wg, 0, wr, lr, lg);
  load_wg(wf1, wg, 1, wr, lr, lg);
  float4 bias[R_][2];
#pragma unroll
  for (int r = 0; r < R_; ++r)
#pragma unroll
    for (int mr = 0; mr < 2; ++mr)
      bias[r][mr] = *(const float4*)(bg + r * C_ + 32 * wr + 16 * mr + 4 * lg);
  gl_chunk(A + Asl0, RB[0], w, lane);          // q0 = r0 ch0
  gl_chunk(A + Asl0 + 4096, RB[1], w, lane);   // q1 = r0 ch1
  __builtin_amdgcn_sched_barrier(0);

  // ---- P0a: X^T bf16 (swizzled) into RB2 space
  u16 (*XT)[64] = (u16(*)[64])RB[2];
  {
    const int c = tid & 63, ub = tid >> 6;
#pragma unroll
    for (int j = 0; j < 8; ++j) {
      const int n0 = 32 * ub + 4 * j;
      XT[n0 + 0][c] = f2bf(xv[j].x);
      XT[n0 + 1][c ^ 16] = f2bf(xv[j].y);
      XT[n0 + 2][c ^ 32] = f2bf(xv[j].z);
      XT[n0 + 3][c ^ 48] = f2bf(xv[j].w);
    }
  }
  BAR();

  f32x4 accA[2][4] = {};
  f32x4 accB[2][4] = {};
  float4 gvA[4], gvB[4];

  // ---- P0b: bfrx <- XT (RB2); mm1 r0 -> TMP (disjoint regions). RB2 dead after.
  bf16x8 bfrx[2][4];
#pragma unroll
  for (int kk = 0; kk < 2; ++kk)
#pragma unroll
    for (int nc = 0; nc < 4; ++nc) {
      const int n = 64 * wc + 16 * nc + lr;
      const int col = (32 * kk + 8 * lg) ^ ((lr & 3) << 4);
      bfrx[kk][nc] = *(const bf16x8*)&XT[n][col];
    }
  mm1f(TMP, wf0, bfrx, bias[0], wr, wc, lr, lg);
  BAR();

  // ---- P1: gl q2 -> RB2; wait q0 (younger loads q1+q2 = 8); consume q0 -> AT0
  gl_chunk(A + Asl0 + 8192, RB[2], w, lane);   // q2 = r0 ch2
  WAITVM(8);
  consume(RB[0], 0, AT[0], outA + Asl0, dscr, tid, gvA);
  BAR();

  // ---- P2: gl q3 -> RB0; K0(AT0); wait q1 (younger q2+q3 = 8); consume q1 -> AT1
  gl_chunk(A + Asl0 + 12288, RB[0], w, lane);  // q3 = r0 ch3
  mm2k(accA, TMP, AT[0], 0, wr, wc, lr, lg);
  WAITVM(8);
  consume(RB[1], 1, AT[1], outA + Asl0, dscr, tid, gvB);
  BAR();

  // ---- P3: gl q4 -> RB1; K1(AT1); wait q2 (younger q3+q4 = 8); consume q2 -> AT0
  gl_chunk(A + Asl1, RB[1], w, lane);          // q4 = r1 ch0
  mm2k(accA, TMP, AT[1], 1, wr, wc, lr, lg);
  WAITVM(8);
  consume(RB[2], 2, AT[0], outA + Asl0, dscr, tid, gvA);
  BAR();

  // ---- P4: gl q5 -> RB2; K2(AT0); wait q3 (younger q4+q5 = 8); consume q3 -> AT1
  gl_chunk(A + Asl1 + 4096, RB[2], w, lane);   // q5 = r1 ch1
  mm2k(accA, TMP, AT[0], 2, wr, wc, lr, lg);
  WAITVM(8);
  consume(RB[0], 3, AT[1], outA + Asl0, dscr, tid, gvB);
  BAR();

  // ---- P5: gl q6 -> RB0; K3(AT1) [accA done]; wait q4 (younger q5+q6 = 8);
  //          consume q4 -> AT0
  gl_chunk(A + Asl1 + 8192, RB[0], w, lane);   // q6 = r1 ch2
  mm2k(accA, TMP, AT[1], 3, wr, wc, lr, lg);
  WAITVM(8);
  consume(RB[1], 0, AT[0], outA + Asl1, dscr + 128, tid, gvA);
  BAR();

  // ---- P6: gl q7 -> RB1; mm1 r1 -> TMP; wait q5 (younger q6+q7 = 8);
  //          consume q5 -> AT1
  gl_chunk(A + Asl1 + 12288, RB[1], w, lane);  // q7 = r1 ch3
  mm1f(TMP, wf1, bfrx, bias[1], wr, wc, lr, lg);
  WAITVM(8);
  consume(RB[2], 1, AT[1], outA + Asl1, dscr + 128, tid, gvB);
  BAR();

  // ---- P7: K0'(AT0 q4)
  mm2k(accB, TMP, AT[0], 0, wr, wc, lr, lg);
  BAR();

  // ---- P8: K1'(AT1 q5); wait q6 (younger loads: q7 = 4); consume q6 -> AT0
  mm2k(accB, TMP, AT[1], 1, wr, wc, lr, lg);
  WAITVM(4);
  consume(RB[0], 2, AT[0], outA + Asl1, dscr + 128, tid, gvA);
  BAR();

  // ---- P9: K2'(AT0 q6); wait q7 (younger loads: none); consume q7 -> AT1
  mm2k(accB, TMP, AT[0], 2, wr, wc, lr, lg);
  WAITVM(0);
  consume(RB[1], 3, AT[1], outA + Asl1, dscr + 128, tid, gvB);
  BAR();

  // ---- P10: K3'(AT1 q7) [accB done]; force dscr stores out before reads
  mm2k(accB, TMP, AT[1], 3, wr, wc, lr, lg);
  WAITVM(0);
  BAR();

  // ---- P11: epilogue: dinv[m] scale, stage (swizzled) in TMP, wsX stores
  float dA[4], dB[4];
#pragma unroll
  for (int nc = 0; nc < 4; ++nc) {
    const int m = 64 * wc + 16 * nc + lr;
    dA[nc] = dscr[m];
    dB[nc] = dscr[128 + m];
  }
  u16* stage = &TMP[0][0];
#pragma unroll
  for (int mr = 0; mr < 2; ++mr)
#pragma unroll
    for (int nc = 0; nc < 4; ++nc) {
      const int m = 64 * wc + 16 * nc + lr;
      const int c0 = 32 * wr + 16 * mr + 4 * lg;
#pragma unroll
      for (int i = 0; i < 4; ++i) {
        const float v = dA[nc] * accA[mr][nc][i] + dB[nc] * accB[mr][nc][i];
        stage[m * 64 + ((c0 + i) ^ ((m & 7) << 3))] = f2bf(v);
      }
    }
  BAR();
  {
    u16* wp = wsX + ((size_t)(b * T_ + t) * N_) * C_;
#pragma unroll
    for (int it = 0; it < 4; ++it) {
      const int idx = it * 2048 + tid * 8;
      const int m = idx >> 6, a = idx & 63;
      u16x8 v = *(const u16x8*)&stage[m * 64 + a];
      *(u16x8*)(wp + m * 64 + (a ^ ((m & 7) << 3))) = v;
    }
  }
}

// ---------------------------------------------------------------------------
// K2 (R16-green): u16x8 staging; per (b,t): h = prelu(x_comb);
// out = prelu(conv3_T(h) + b_tcn + x)
// ---------------------------------------------------------------------------
__global__ __launch_bounds__(256, 3) void k_tcn(
    const u16* __restrict__ wsX, const float* __restrict__ x,
    const float* __restrict__ wt, const float* __restrict__ bt,
    const float* __restrict__ a_tcn, const float* __restrict__ a_out,
    float* __restrict__ out) {
  __shared__ __align__(16) u16 HT[N_][200];
  const int tid = threadIdx.x;
  const int bid = ((blockIdx.x & 7) << 8) | (blockIdx.x >> 3);  // XCD swizzle
  const int b = bid >> 5, t = bid & 31;
  const int lane = tid & 63, wv = tid >> 6;
  const int wr = wv >> 1, wc = wv & 1;
  const int lr = lane & 15, lg = lane >> 4;
  const float at = a_tcn[0], ao = a_out[0];

  bf16x8 wfr[6][2];
#pragma unroll
  for (int kq = 0; kq < 6; ++kq) {
    const int dt = kq >> 1;
    const int ci0 = (32 * kq + 8 * lg) & 63;
#pragma unroll
    for (int mr = 0; mr < 2; ++mr) {
      const int co = 32 * wr + 16 * mr + lr;
      const float* p = wt + ((size_t)co * C_ + ci0) * 3 + dt;
      float e[8];
#pragma unroll
      for (int j = 0; j < 8; ++j) e[j] = p[3 * j];
      bf16x8 f;
#pragma unroll
      for (int j = 0; j < 8; ++j) f[j] = (short)f2bf(e[j]);
      wfr[kq][mr] = f;
    }
  }

#pragma unroll
  for (int dt = 0; dt < 3; ++dt) {
    const int t2 = t + dt - 1;
    const bool ok = (t2 >= 0) && (t2 < T_);
    const u16* p = wsX + ((size_t)(b * T_ + (ok ? t2 : 0)) * N_) * C_;
    u16x8 hv[4];
#pragma unroll
    for (int i3 = 0; i3 < 4; ++i3) {
      const int idx = i3 * 256 + tid;
      const int n = idx >> 3, c8 = (idx & 7) * 8;
      u16x8 z = {0, 0, 0, 0, 0, 0, 0, 0};
      hv[i3] = ok ? *(const u16x8*)(p + n * C_ + c8) : z;
    }
#pragma unroll
    for (int i3 = 0; i3 < 4; ++i3) {
      const int idx = i3 * 256 + tid;
      const int n = idx >> 3, c8 = (idx & 7) * 8;
      u16x8 o;
#pragma unroll
      for (int j = 0; j < 8; ++j) {
        float f = bf2f((u16)hv[i3][j]);
        o[j] = f2bf(f < 0.f ? at * f : f);
      }
      *(u16x8*)&HT[n][dt * 64 + c8] = o;
    }
  }
  __syncthreads();

  f32x4 acc[2][4] = {};
#pragma unroll
  for (int kq = 0; kq < 6; ++kq) {
    bf16x8 bfr[4];
#pragma unroll
    for (int nc = 0; nc < 4; ++nc)
      bfr[nc] = *(const bf16x8*)&HT[64 * wc + 16 * nc + lr][32 * kq + 8 * lg];
#pragma unroll
    for (int mr = 0; mr < 2; ++mr)
#pragma unroll
      for (int nc = 0; nc < 4; ++nc)
        acc[mr][nc] = MFMA(wfr[kq][mr], bfr[nc], acc[mr][nc], 0, 0, 0);
  }

#pragma unroll
  for (int mr = 0; mr < 2; ++mr) {
    const int co0 = 32 * wr + 16 * mr + 4 * lg;
    float bts[4];
#pragma unroll
    for (int i = 0; i < 4; ++i) bts[i] = bt[co0 + i];
#pragma unroll
    for (int nc = 0; nc < 4; ++nc) {
      const int n = 64 * wc + 16 * nc + lr;
#pragma unroll
      for (int i = 0; i < 4; ++i) {
        const size_t gi = ((size_t)(b * C_ + co0 + i) * T_ + t) * N_ + n;
        float v = acc[mr][nc][i] + bts[i] + x[gi];
        out[gi] = (v < 0.f) ? ao * v : v;
      }
    }
  }
}

extern "C" void kernel_launch(void* const* d_in, const int* in_sizes, int n_in,
                              void* d_out, int out_size, void* d_ws, size_t ws_size,
                              hipStream_t stream) {
  const float* x = (const float*)d_in[0];
  const float* A = (const float*)d_in[1];
  const float* wg = (const float*)d_in[2];
  const float* bg = (const float*)d_in[3];
  const float* wt = (const float*)d_in[4];
  const float* bt = (const float*)d_in[5];
  const float* atc = (const float*)d_in[6];
  const float* aoc = (const float*)d_in[7];
  float* out = (float*)d_out;
  float* outA = out + (size_t)B_ * C_ * T_ * N_;  // second tuple element: A copy
  u16* wsX = (u16*)d_ws;                          // bf16 x_comb, (B,T,N,C)
  float* dscr = out;  // dinv scratch inside out-main; k_tcn overwrites it all

  k_gcn<<<B_ * T_, 256, 0, stream>>>(x, A, wg, bg, outA, wsX, dscr);
  k_tcn<<<B_ * T_, 256, 0, stream>>>(wsX, x, wt, bt, atc, aoc, out);
}

// Round 18
// 200.239 us; speedup vs baseline: 1.0393x; 1.0393x over previous
//
#include <hip/hip_runtime.h>
#include <hip/hip_bf16.h>

typedef unsigned short u16;
typedef unsigned int u32;
typedef __attribute__((ext_vector_type(8))) short bf16x8;
typedef __attribute__((ext_vector_type(4))) float f32x4;
typedef __attribute__((ext_vector_type(4))) u16 u16x4;
typedef __attribute__((ext_vector_type(8))) u16 u16x8;

#define B_ 64
#define R_ 2
#define T_ 32
#define N_ 128
#define C_ 64

__device__ __forceinline__ u16 f2bf(float f) {
  return __builtin_bit_cast(u16, __float2bfloat16(f));
}
__device__ __forceinline__ float bf2f(u16 h) {
  u32 u = ((u32)h) << 16;
  return __builtin_bit_cast(float, u);
}

#define MFMA __builtin_amdgcn_mfma_f32_16x16x32_bf16

#define STG16(gsrc, ldst)                                                   \
  __builtin_amdgcn_global_load_lds(                                         \
      (const __attribute__((address_space(1))) u32*)(gsrc),                 \
      (__attribute__((address_space(3))) u32*)(ldst), 16, 0, 0)

// barrier that does NOT drain vmcnt
#define BAR()                                                  \
  do {                                                         \
    asm volatile("s_waitcnt lgkmcnt(0)" ::: "memory");         \
    __builtin_amdgcn_s_barrier();                              \
    __builtin_amdgcn_sched_barrier(0);                         \
  } while (0)

// counted vmcnt wait. N = number of LOADS issued after the op we need
// complete (stores may retire early/out-of-order on CDNA -> never counted).
#define WAITVM(N)                                              \
  do {                                                         \
    asm volatile("s_waitcnt vmcnt(" #N ")" ::: "memory");      \
    __builtin_amdgcn_sched_barrier(0);                         \
  } while (0)

// ---- issue one 16KB chunk (32 rows x 128 f32) via global_load_lds.
// R18: CONTIGUOUS source (granule d -> slot d, row-major). Each wave-instr
// reads 1KB contiguous (full cache lines) instead of 64 scattered 16B
// requests at 512B stride -- the request-rate fix.
__device__ __forceinline__ void gl_chunk(const float* Abase, float* rb,
                                         int w, int lane) {
#pragma unroll
  for (int g = 0; g < 4; ++g) {
    const int d = (w * 4 + g) * 64 + lane;     // granule index 0..1023
    STG16(Abase + d * 4, rb + (w * 4 + g) * 256);
  }
}

// ---- consume a landed chunk: thread owns a 4x4 f32 block (rows rb8*4..+3,
// cols c4*4..+3). RB is row-major: granule (r,c4) at f4-slot r*32 + c4.
// 4-way LDS bank conflict on the b128 reads (4 reads/thread) -- accepted,
// ~1.58x on a tiny phase fraction, in exchange for contiguous HBM requests.
__device__ __forceinline__ void consume(const float* rb, int ch,
                                        u16 (*ATb)[32], float* outAs,
                                        float* dscr, int tid, float4* gv) {
  const int c4 = tid & 31, rb8 = tid >> 5;
  const float4* rf4 = (const float4*)rb;
#pragma unroll
  for (int j = 0; j < 4; ++j)
    gv[j] = rf4[((rb8 << 2) + j) * 32 + c4];
  float d4[4];
#pragma unroll
  for (int j = 0; j < 4; ++j) {
    float s = (gv[j].x + gv[j].y) + (gv[j].z + gv[j].w);
    s += __shfl_xor(s, 1); s += __shfl_xor(s, 2); s += __shfl_xor(s, 4);
    s += __shfl_xor(s, 8); s += __shfl_xor(s, 16);
    d4[j] = rsqrtf(s + 1.0f);
  }
  if (c4 == 0) {
    float4 dv = {d4[0], d4[1], d4[2], d4[3]};
    *(float4*)(dscr + ch * 32 + rb8 * 4) = dv;
  }
#pragma unroll
  for (int j = 0; j < 4; ++j)
    *(float4*)(outAs + (size_t)(ch * 32 + rb8 * 4 + j) * N_ + c4 * 4) = gv[j];
  const int nb = (rb8 << 2) ^ ((c4 & 7) << 2);
#pragma unroll
  for (int i = 0; i < 4; ++i) {
    const int m = c4 * 4 + i;
    u16x4 pk;
#pragma unroll
    for (int j = 0; j < 4; ++j) {
      float v = ((const float*)&gv[j])[i];
      if (m == ch * 32 + rb8 * 4 + j) v += 1.0f;
      pk[j] = f2bf(v * d4[j]);
    }
    *(u16x4*)&ATb[m][nb] = pk;
  }
}

__device__ __forceinline__ void load_wg(bf16x8 wf[2][2], const float* wg, int r,
                                        int wr, int lr, int lg) {
#pragma unroll
  for (int kk = 0; kk < 2; ++kk)
#pragma unroll
    for (int mr = 0; mr < 2; ++mr) {
      const float* p = wg + ((size_t)(r * C_ + 32 * wr + 16 * mr + lr)) * C_ + 32 * kk + 8 * lg;
      float4 a = *(const float4*)p, b = *(const float4*)(p + 4);
      bf16x8 f;
      f[0] = (short)f2bf(a.x); f[1] = (short)f2bf(a.y);
      f[2] = (short)f2bf(a.z); f[3] = (short)f2bf(a.w);
      f[4] = (short)f2bf(b.x); f[5] = (short)f2bf(b.y);
      f[6] = (short)f2bf(b.z); f[7] = (short)f2bf(b.w);
      wf[kk][mr] = f;
    }
}

// mm1: TMP[o][n ^ ((o&3)<<4)] = sum_c W[o][c]*X[c][n] + bias[o]
__device__ __forceinline__ void mm1f(u16 (*TMP)[128], const bf16x8 wf[2][2],
                                     const bf16x8 bfr[2][4], const float4 bias[2],
                                     int wr, int wc, int lr, int lg) {
  f32x4 acc1[2][4] = {};
#pragma unroll
  for (int kk = 0; kk < 2; ++kk)
#pragma unroll
    for (int mr = 0; mr < 2; ++mr)
#pragma unroll
      for (int nc = 0; nc < 4; ++nc)
        acc1[mr][nc] = MFMA(wf[kk][mr], bfr[kk][nc], acc1[mr][nc], 0, 0, 0);
#pragma unroll
  for (int mr = 0; mr < 2; ++mr) {
    const int o0 = 32 * wr + 16 * mr + 4 * lg;
    const float bb[4] = {bias[mr].x, bias[mr].y, bias[mr].z, bias[mr].w};
#pragma unroll
    for (int nc = 0; nc < 4; ++nc) {
      const int n = 64 * wc + 16 * nc + lr;
#pragma unroll
      for (int i = 0; i < 4; ++i)
        TMP[o0 + i][n ^ (i << 4)] = f2bf(acc1[mr][nc][i] + bb[i]);
    }
  }
}

// one K=32 mm2 step for chunk ch (R10-proven)
__device__ __forceinline__ void mm2k(f32x4 acc[2][4], const u16 (*TMP)[128],
                                     const u16 (*ATb)[32], int ch,
                                     int wr, int wc, int lr, int lg) {
  bf16x8 af[2], bfr[4];
#pragma unroll
  for (int mr = 0; mr < 2; ++mr) {
    const int c = 32 * wr + 16 * mr + lr;
    const int colT = (ch * 32 + 8 * lg) ^ ((lr & 3) << 4);
    af[mr] = *(const bf16x8*)&TMP[c][colT];
  }
#pragma unroll
  for (int nc = 0; nc < 4; ++nc) {
    const int m = 64 * wc + 16 * nc + lr;
    const int swz = ((m >> 2) & 7) << 2;
    const int base = (8 * lg) ^ (swz & 24);
    const int s4 = swz & 4;
    u16x4 h0 = *(const u16x4*)&ATb[m][base + s4];
    u16x4 h1 = *(const u16x4*)&ATb[m][base + (4 ^ s4)];
    bf16x8 f;
    f[0] = (short)h0[0]; f[1] = (short)h0[1]; f[2] = (short)h0[2]; f[3] = (short)h0[3];
    f[4] = (short)h1[0]; f[5] = (short)h1[1]; f[6] = (short)h1[2]; f[7] = (short)h1[3];
    bfr[nc] = f;
  }
#pragma unroll
  for (int mr = 0; mr < 2; ++mr)
#pragma unroll
    for (int nc = 0; nc < 4; ++nc)
      acc[mr][nc] = MFMA(af[mr], bfr[nc], acc[mr][nc], 0, 0, 0);
}

// ---------------------------------------------------------------------------
// K1 (R18): R17 schedule (green), RB layout row-major + contiguous gl_chunk.
// LDS = 49152+16384+16384 = 81920 -> 2 blocks/CU; VGPR ~100 (no spill).
// ---------------------------------------------------------------------------
__global__ __launch_bounds__(256, 2) void k_gcn(
    const float* __restrict__ x, const float* __restrict__ A,
    const float* __restrict__ wg, const float* __restrict__ bg,
    float* __restrict__ outA, u16* __restrict__ wsX, float* __restrict__ dscrg) {
  __shared__ __align__(16) float RB[3][32 * 128];
  __shared__ __align__(16) u16 AT[2][N_][32];
  __shared__ __align__(16) u16 TMP[C_][128];

  const int tid = threadIdx.x;
  const int bid = ((blockIdx.x & 7) << 8) | (blockIdx.x >> 3);  // XCD swizzle
  const int b = bid >> 5, t = bid & 31;
  const int lane = tid & 63, w = tid >> 6;
  const int wr = w >> 1, wc = w & 1;
  const int lr = lane & 15, lg = lane >> 4;

  const size_t Asl0 = ((size_t)((b * R_ + 0) * T_ + t)) * (size_t)(N_ * N_);
  const size_t Asl1 = ((size_t)((b * R_ + 1) * T_ + t)) * (size_t)(N_ * N_);
  float* dscr = dscrg + (size_t)bid * 256;  // [2][128] per pair, in out-main

  // ---- prologue: xv, weights, bias; issue q0 -> RB0, q1 -> RB1
  float4 xv[8];
  {
    const int c = tid & 63, ub = tid >> 6;
    const float* xp = x + ((size_t)(b * C_ + c) * T_ + t) * N_ + 32 * ub;
#pragma unroll
    for (int j = 0; j < 8; ++j) xv[j] = *(const float4*)(xp + 4 * j);
  }
  bf16x8 wf0[2][2], wf1[2][2];
  load_wg(wf0, wg, 0, wr, lr, lg);
  load_wg(wf1, wg, 1, wr, lr, lg);
  float4 bias[R_][2];
#pragma unroll
  for (int r = 0; r < R_; ++r)
#pragma unroll
    for (int mr = 0; mr < 2; ++mr)
      bias[r][mr] = *(const float4*)(bg + r * C_ + 32 * wr + 16 * mr + 4 * lg);
  gl_chunk(A + Asl0, RB[0], w, lane);          // q0 = r0 ch0
  gl_chunk(A + Asl0 + 4096, RB[1], w, lane);   // q1 = r0 ch1
  __builtin_amdgcn_sched_barrier(0);

  // ---- P0a: X^T bf16 (swizzled) into RB2 space
  u16 (*XT)[64] = (u16(*)[64])RB[2];
  {
    const int c = tid & 63, ub = tid >> 6;
#pragma unroll
    for (int j = 0; j < 8; ++j) {
      const int n0 = 32 * ub + 4 * j;
      XT[n0 + 0][c] = f2bf(xv[j].x);
      XT[n0 + 1][c ^ 16] = f2bf(xv[j].y);
      XT[n0 + 2][c ^ 32] = f2bf(xv[j].z);
      XT[n0 + 3][c ^ 48] = f2bf(xv[j].w);
    }
  }
  BAR();

  f32x4 accA[2][4] = {};
  f32x4 accB[2][4] = {};
  float4 gvA[4], gvB[4];

  // ---- P0b: bfrx <- XT (RB2); mm1 r0 -> TMP. RB2 dead after.
  bf16x8 bfrx[2][4];
#pragma unroll
  for (int kk = 0; kk < 2; ++kk)
#pragma unroll
    for (int nc = 0; nc < 4; ++nc) {
      const int n = 64 * wc + 16 * nc + lr;
      const int col = (32 * kk + 8 * lg) ^ ((lr & 3) << 4);
      bfrx[kk][nc] = *(const bf16x8*)&XT[n][col];
    }
  mm1f(TMP, wf0, bfrx, bias[0], wr, wc, lr, lg);
  BAR();

  // ---- P1: gl q2 -> RB2; wait q0 (younger loads q1+q2 = 8); consume q0 -> AT0
  gl_chunk(A + Asl0 + 8192, RB[2], w, lane);   // q2 = r0 ch2
  WAITVM(8);
  consume(RB[0], 0, AT[0], outA + Asl0, dscr, tid, gvA);
  BAR();

  // ---- P2: gl q3 -> RB0; K0(AT0); wait q1 (younger q2+q3 = 8); consume q1 -> AT1
  gl_chunk(A + Asl0 + 12288, RB[0], w, lane);  // q3 = r0 ch3
  mm2k(accA, TMP, AT[0], 0, wr, wc, lr, lg);
  WAITVM(8);
  consume(RB[1], 1, AT[1], outA + Asl0, dscr, tid, gvB);
  BAR();

  // ---- P3: gl q4 -> RB1; K1(AT1); wait q2 (younger q3+q4 = 8); consume q2 -> AT0
  gl_chunk(A + Asl1, RB[1], w, lane);          // q4 = r1 ch0
  mm2k(accA, TMP, AT[1], 1, wr, wc, lr, lg);
  WAITVM(8);
  consume(RB[2], 2, AT[0], outA + Asl0, dscr, tid, gvA);
  BAR();

  // ---- P4: gl q5 -> RB2; K2(AT0); wait q3 (younger q4+q5 = 8); consume q3 -> AT1
  gl_chunk(A + Asl1 + 4096, RB[2], w, lane);   // q5 = r1 ch1
  mm2k(accA, TMP, AT[0], 2, wr, wc, lr, lg);
  WAITVM(8);
  consume(RB[0], 3, AT[1], outA + Asl0, dscr, tid, gvB);
  BAR();

  // ---- P5: gl q6 -> RB0; K3(AT1) [accA done]; wait q4 (younger q5+q6 = 8);
  //          consume q4 -> AT0
  gl_chunk(A + Asl1 + 8192, RB[0], w, lane);   // q6 = r1 ch2
  mm2k(accA, TMP, AT[1], 3, wr, wc, lr, lg);
  WAITVM(8);
  consume(RB[1], 0, AT[0], outA + Asl1, dscr + 128, tid, gvA);
  BAR();

  // ---- P6: gl q7 -> RB1; mm1 r1 -> TMP; wait q5 (younger q6+q7 = 8);
  //          consume q5 -> AT1
  gl_chunk(A + Asl1 + 12288, RB[1], w, lane);  // q7 = r1 ch3
  mm1f(TMP, wf1, bfrx, bias[1], wr, wc, lr, lg);
  WAITVM(8);
  consume(RB[2], 1, AT[1], outA + Asl1, dscr + 128, tid, gvB);
  BAR();

  // ---- P7: K0'(AT0 q4)
  mm2k(accB, TMP, AT[0], 0, wr, wc, lr, lg);
  BAR();

  // ---- P8: K1'(AT1 q5); wait q6 (younger loads: q7 = 4); consume q6 -> AT0
  mm2k(accB, TMP, AT[1], 1, wr, wc, lr, lg);
  WAITVM(4);
  consume(RB[0], 2, AT[0], outA + Asl1, dscr + 128, tid, gvA);
  BAR();

  // ---- P9: K2'(AT0 q6); wait q7 (younger loads: none); consume q7 -> AT1
  mm2k(accB, TMP, AT[0], 2, wr, wc, lr, lg);
  WAITVM(0);
  consume(RB[1], 3, AT[1], outA + Asl1, dscr + 128, tid, gvB);
  BAR();

  // ---- P10: K3'(AT1 q7) [accB done]; force dscr stores out before reads
  mm2k(accB, TMP, AT[1], 3, wr, wc, lr, lg);
  WAITVM(0);
  BAR();

  // ---- P11: epilogue: dinv[m] scale, stage (swizzled) in TMP, wsX stores
  float dA[4], dB[4];
#pragma unroll
  for (int nc = 0; nc < 4; ++nc) {
    const int m = 64 * wc + 16 * nc + lr;
    dA[nc] = dscr[m];
    dB[nc] = dscr[128 + m];
  }
  u16* stage = &TMP[0][0];
#pragma unroll
  for (int mr = 0; mr < 2; ++mr)
#pragma unroll
    for (int nc = 0; nc < 4; ++nc) {
      const int m = 64 * wc + 16 * nc + lr;
      const int c0 = 32 * wr + 16 * mr + 4 * lg;
#pragma unroll
      for (int i = 0; i < 4; ++i) {
        const float v = dA[nc] * accA[mr][nc][i] + dB[nc] * accB[mr][nc][i];
        stage[m * 64 + ((c0 + i) ^ ((m & 7) << 3))] = f2bf(v);
      }
    }
  BAR();
  {
    u16* wp = wsX + ((size_t)(b * T_ + t) * N_) * C_;
#pragma unroll
    for (int it = 0; it < 4; ++it) {
      const int idx = it * 2048 + tid * 8;
      const int m = idx >> 6, a = idx & 63;
      u16x8 v = *(const u16x8*)&stage[m * 64 + a];
      *(u16x8*)(wp + m * 64 + (a ^ ((m & 7) << 3))) = v;
    }
  }
}

// ---------------------------------------------------------------------------
// K2 (R16-green): u16x8 staging; per (b,t): h = prelu(x_comb);
// out = prelu(conv3_T(h) + b_tcn + x)
// ---------------------------------------------------------------------------
__global__ __launch_bounds__(256, 3) void k_tcn(
    const u16* __restrict__ wsX, const float* __restrict__ x,
    const float* __restrict__ wt, const float* __restrict__ bt,
    const float* __restrict__ a_tcn, const float* __restrict__ a_out,
    float* __restrict__ out) {
  __shared__ __align__(16) u16 HT[N_][200];
  const int tid = threadIdx.x;
  const int bid = ((blockIdx.x & 7) << 8) | (blockIdx.x >> 3);  // XCD swizzle
  const int b = bid >> 5, t = bid & 31;
  const int lane = tid & 63, wv = tid >> 6;
  const int wr = wv >> 1, wc = wv & 1;
  const int lr = lane & 15, lg = lane >> 4;
  const float at = a_tcn[0], ao = a_out[0];

  bf16x8 wfr[6][2];
#pragma unroll
  for (int kq = 0; kq < 6; ++kq) {
    const int dt = kq >> 1;
    const int ci0 = (32 * kq + 8 * lg) & 63;
#pragma unroll
    for (int mr = 0; mr < 2; ++mr) {
      const int co = 32 * wr + 16 * mr + lr;
      const float* p = wt + ((size_t)co * C_ + ci0) * 3 + dt;
      float e[8];
#pragma unroll
      for (int j = 0; j < 8; ++j) e[j] = p[3 * j];
      bf16x8 f;
#pragma unroll
      for (int j = 0; j < 8; ++j) f[j] = (short)f2bf(e[j]);
      wfr[kq][mr] = f;
    }
  }

#pragma unroll
  for (int dt = 0; dt < 3; ++dt) {
    const int t2 = t + dt - 1;
    const bool ok = (t2 >= 0) && (t2 < T_);
    const u16* p = wsX + ((size_t)(b * T_ + (ok ? t2 : 0)) * N_) * C_;
    u16x8 hv[4];
#pragma unroll
    for (int i3 = 0; i3 < 4; ++i3) {
      const int idx = i3 * 256 + tid;
      const int n = idx >> 3, c8 = (idx & 7) * 8;
      u16x8 z = {0, 0, 0, 0, 0, 0, 0, 0};
      hv[i3] = ok ? *(const u16x8*)(p + n * C_ + c8) : z;
    }
#pragma unroll
    for (int i3 = 0; i3 < 4; ++i3) {
      const int idx = i3 * 256 + tid;
      const int n = idx >> 3, c8 = (idx & 7) * 8;
      u16x8 o;
#pragma unroll
      for (int j = 0; j < 8; ++j) {
        float f = bf2f((u16)hv[i3][j]);
        o[j] = f2bf(f < 0.f ? at * f : f);
      }
      *(u16x8*)&HT[n][dt * 64 + c8] = o;
    }
  }
  __syncthreads();

  f32x4 acc[2][4] = {};
#pragma unroll
  for (int kq = 0; kq < 6; ++kq) {
    bf16x8 bfr[4];
#pragma unroll
    for (int nc = 0; nc < 4; ++nc)
      bfr[nc] = *(const bf16x8*)&HT[64 * wc + 16 * nc + lr][32 * kq + 8 * lg];
#pragma unroll
    for (int mr = 0; mr < 2; ++mr)
#pragma unroll
      for (int nc = 0; nc < 4; ++nc)
        acc[mr][nc] = MFMA(wfr[kq][mr], bfr[nc], acc[mr][nc], 0, 0, 0);
  }

#pragma unroll
  for (int mr = 0; mr < 2; ++mr) {
    const int co0 = 32 * wr + 16 * mr + 4 * lg;
    float bts[4];
#pragma unroll
    for (int i = 0; i < 4; ++i) bts[i] = bt[co0 + i];
#pragma unroll
    for (int nc = 0; nc < 4; ++nc) {
      const int n = 64 * wc + 16 * nc + lr;
#pragma unroll
      for (int i = 0; i < 4; ++i) {
        const size_t gi = ((size_t)(b * C_ + co0 + i) * T_ + t) * N_ + n;
        float v = acc[mr][nc][i] + bts[i] + x[gi];
        out[gi] = (v < 0.f) ? ao * v : v;
      }
    }
  }
}

extern "C" void kernel_launch(void* const* d_in, const int* in_sizes, int n_in,
                              void* d_out, int out_size, void* d_ws, size_t ws_size,
                              hipStream_t stream) {
  const float* x = (const float*)d_in[0];
  const float* A = (const float*)d_in[1];
  const float* wg = (const float*)d_in[2];
  const float* bg = (const float*)d_in[3];
  const float* wt = (const float*)d_in[4];
  const float* bt = (const float*)d_in[5];
  const float* atc = (const float*)d_in[6];
  const float* aoc = (const float*)d_in[7];
  float* out = (float*)d_out;
  float* outA = out + (size_t)B_ * C_ * T_ * N_;  // second tuple element: A copy
  u16* wsX = (u16*)d_ws;                          // bf16 x_comb, (B,T,N,C)
  float* dscr = out;  // dinv scratch inside out-main; k_tcn overwrites it all

  k_gcn<<<B_ * T_, 256, 0, stream>>>(x, A, wg, bg, outA, wsX, dscr);
  k_tcn<<<B_ * T_, 256, 0, stream>>>(wsX, x, wt, bt, atc, aoc, out);
}